// Round 5
// baseline (3522.824 us; speedup 1.0000x reference)
//
#include <hip/hip_runtime.h>
#include <hip/hip_bf16.h>

// SAGEClassifier: h[50000,256] --conv1(LSTM-agg)--> h1[50000,128] --conv2--> h2[50000,128]
//   --segment_max(256 graphs)--> hg[256,128] --linear--> out[256,10]
//
// Round 5: fix the two real LSTM limiters found in round-4 counters:
//  (a) c[dc] was runtime-indexed (unroll-1 loop) -> scratch (WRITE_SIZE 600MB). Now
//      dc is a compile-time unrolled loop; c statically indexed.
//  (b) prefetch gathers poisoned vmcnt FIFO ahead of W loads. Now staging uses
//      global_load_lds issued AFTER the kk-loop (sched_barrier fence), draining at
//      the end-of-iter barrier; zero staging VGPRs.
//  + hinS XOR-swizzled via pre-swizzled GLOBAL source (gload dest stays linear),
//  + W pre-packed so each wave's 4 B-frags are one contiguous coalesced 1KB chunk,
//  + LDS diet: 52.2KB -> 3 blocks/CU conv1 (4 conv2), launch_bounds(256,3/4),
//  + exp2/rcp-based gates.

#define NNODES  50000
#define DEG     16
#define INDIM   256
#define HIDDIM  128
#define NCLS    10
#define NGRAPH  256

typedef __hip_bfloat16 bf16;
typedef short bf16x8 __attribute__((ext_vector_type(8)));
typedef float f32x4  __attribute__((ext_vector_type(4)));

__device__ __forceinline__ float sigf(float x) {
    // 1/(1+2^(-x*log2e)); inf-safe at both ends
    float e = __builtin_amdgcn_exp2f(-1.44269504f * x);
    return __builtin_amdgcn_rcpf(1.0f + e);
}
__device__ __forceinline__ float tanhf_(float x) {
    x = fminf(fmaxf(x, -10.f), 10.f);                    // keep e finite (inf*0=NaN)
    float e = __builtin_amdgcn_exp2f(2.88539008f * x);   // 2^(2x*log2e) = e^(2x)
    return (e - 1.0f) * __builtin_amdgcn_rcpf(e + 1.0f);
}
__device__ __forceinline__ float b2f(unsigned short u) {
    return __uint_as_float(((unsigned)u) << 16);
}
__device__ __forceinline__ unsigned short f2b(float f) {  // RNE bf16
    unsigned u = __float_as_uint(f);
    return (unsigned short)((u + 0x7FFF + ((u >> 16) & 1)) >> 16);
}

typedef __attribute__((address_space(3))) unsigned int lds_u32;
typedef const __attribute__((address_space(1))) unsigned int glb_u32;
__device__ __forceinline__ void gload_lds16(const unsigned short* g, unsigned short* l) {
    __builtin_amdgcn_global_load_lds((glb_u32*)g, (lds_u32*)l, 16, 0, 0);
}

__global__ void f2bf_k(const float* __restrict__ in, unsigned short* __restrict__ out, int n) {
    int i = blockIdx.x * 256 + threadIdx.x;
    if (i < n) out[i] = f2b(in[i]);
}

// Pack W_hh [4D,D] fp32 -> per-(g,dc,wid,kk) contiguous 512-short chunks of bf16
// out[((((g*DCH+dc)*4+wid)*KCH+kk)*16+lr)*32 + lg*8 + j] = W[(g*D+dc*64+wid*16+lr)*D + kk*32+lg*8+j]
__global__ void packw_k(const float* __restrict__ W, unsigned short* __restrict__ out,
                        int D, int ksh, int dsh) {
    int o = blockIdx.x * 256 + threadIdx.x;
    if (o >= 4 * D * D) return;
    int j  = o & 7;
    int lg = (o >> 3) & 3;
    int lr = (o >> 5) & 15;
    int cch = o >> 9;
    int kk = cch & ((1 << ksh) - 1);
    int c2 = cch >> ksh;
    int wd = c2 & 3;
    int c3 = c2 >> 2;
    int dc = c3 & ((1 << dsh) - 1);
    int g  = c3 >> dsh;
    int row = g * D + dc * 64 + wd * 16 + lr;
    int col = kk * 32 + lg * 8 + j;
    out[o] = f2b(W[row * D + col]);
}

// ---------------- fp32 tiled GEMM (unchanged) ----------------
template<bool RELU, bool DUAL, bool BF16OUT>
__global__ __launch_bounds__(256) void gemm_nt(
    const float* __restrict__ A, const float* __restrict__ B,
    const float* __restrict__ A2, const float* __restrict__ B2,
    const float* __restrict__ bias0, const float* __restrict__ bias1,
    void* __restrict__ Cout, int M, int Ncol, int K, int K2)
{
    __shared__ float As[16][68];
    __shared__ float Bs[16][68];
    const int tid = threadIdx.x;
    const int m0 = blockIdx.y * 64;
    const int j0 = blockIdx.x * 64;
    const int tx = tid & 15;
    const int ty = tid >> 4;
    const int am = tid >> 2;
    const int ak = (tid & 3) * 4;
    float c[4][4] = {};

    const int npass = DUAL ? 2 : 1;
    for (int pass = 0; pass < npass; ++pass) {
        const float* Ap = (DUAL && pass) ? A2 : A;
        const float* Bp = (DUAL && pass) ? B2 : B;
        const int Kp = (DUAL && pass) ? K2 : K;
        for (int kk = 0; kk < Kp; kk += 16) {
            float4 av = make_float4(0.f, 0.f, 0.f, 0.f);
            float4 bv = make_float4(0.f, 0.f, 0.f, 0.f);
            if (m0 + am < M)    av = *(const float4*)&Ap[(size_t)(m0 + am) * Kp + kk + ak];
            if (j0 + am < Ncol) bv = *(const float4*)&Bp[(size_t)(j0 + am) * Kp + kk + ak];
            __syncthreads();
            As[ak + 0][am] = av.x; As[ak + 1][am] = av.y;
            As[ak + 2][am] = av.z; As[ak + 3][am] = av.w;
            Bs[ak + 0][am] = bv.x; Bs[ak + 1][am] = bv.y;
            Bs[ak + 2][am] = bv.z; Bs[ak + 3][am] = bv.w;
            __syncthreads();
            #pragma unroll
            for (int k = 0; k < 16; ++k) {
                float4 a = *(const float4*)&As[k][ty * 4];
                float4 b = *(const float4*)&Bs[k][tx * 4];
                c[0][0] = fmaf(a.x, b.x, c[0][0]); c[0][1] = fmaf(a.x, b.y, c[0][1]);
                c[0][2] = fmaf(a.x, b.z, c[0][2]); c[0][3] = fmaf(a.x, b.w, c[0][3]);
                c[1][0] = fmaf(a.y, b.x, c[1][0]); c[1][1] = fmaf(a.y, b.y, c[1][1]);
                c[1][2] = fmaf(a.y, b.z, c[1][2]); c[1][3] = fmaf(a.y, b.w, c[1][3]);
                c[2][0] = fmaf(a.z, b.x, c[2][0]); c[2][1] = fmaf(a.z, b.y, c[2][1]);
                c[2][2] = fmaf(a.z, b.z, c[2][2]); c[2][3] = fmaf(a.z, b.w, c[2][3]);
                c[3][0] = fmaf(a.w, b.x, c[3][0]); c[3][1] = fmaf(a.w, b.y, c[3][1]);
                c[3][2] = fmaf(a.w, b.z, c[3][2]); c[3][3] = fmaf(a.w, b.w, c[3][3]);
            }
        }
    }
    #pragma unroll
    for (int i = 0; i < 4; ++i) {
        int m = m0 + ty * 4 + i;
        if (m >= M) continue;
        #pragma unroll
        for (int jj = 0; jj < 4; ++jj) {
            int j = j0 + tx * 4 + jj;
            if (j >= Ncol) continue;
            float v = c[i][jj];
            if (bias0) v += bias0[j];
            if (bias1) v += bias1[j];
            if (RELU) v = fmaxf(v, 0.f);
            if (BF16OUT) ((bf16*)Cout)[(size_t)m * Ncol + j] = __float2bfloat16(v);
            else         ((float*)Cout)[(size_t)m * Ncol + j] = v;
        }
    }
}

// ---------------- pipelined MFMA fused LSTM ----------------
// 32 nodes/block, 4 waves. Wave w owns d-cols [w*16,w*16+16) of each 64-chunk, all
// 4 gates -> i/f/g/o of a (node,d) share a lane+reg. C-frag: node=m*16+(lane>>4)*4+reg,
// d = dc*64 + w*16 + (lane&15).
// hinS: [32 rows][4g x 64c] bf16, XOR-swizzled: physical col16 = logical ^ (row&7),
// realized by pre-swizzling the global gather address (gload_lds dest stays linear).
template<int D, int MINW>
__global__ __launch_bounds__(256, MINW) void lstm_mfma(
    const unsigned short* __restrict__ Hin,   // [Nn,4D] bf16 bits (bias folded)
    const unsigned short* __restrict__ Wbp,   // packed W_hh bf16 (packw_k layout)
    const int* __restrict__ nidx,             // [Nn,DEG]
    float* __restrict__ hout,                 // [Nn,D]
    int Nn)
{
    constexpr int FD  = 4 * D;
    constexpr int KCH = D / 32;
    constexpr int DCH = D / 64;
    constexpr int TN  = 32;
    constexpr int MT  = 2;
    constexpr int LDA = D + 8;
    constexpr int GST = DCH * 4 * KCH * 512;   // g-stride in packed W (shorts)

    __shared__ unsigned short hS[2][TN * LDA];   // dbuf h_state
    __shared__ unsigned short hinS[TN * 256];    // single-buffer gathered Hin slice
    __shared__ int nidS[TN * DEG];

    const int tid  = threadIdx.x;
    const int wid  = tid >> 6;
    const int lane = tid & 63;
    const int lg   = lane >> 4;
    const int lr   = lane & 15;
    const int nb   = blockIdx.x * TN;

    for (int i = tid; i < TN * DEG; i += 256) {
        int node = nb + (i >> 4);
        nidS[i] = (node < Nn) ? nidx[node * DEG + (i & 15)] : 0;
    }

    // identity B-fragment: B[col=lr][k=lg*8+j] = (lg*8+j == lr)
    bf16x8 bI;
    #pragma unroll
    for (int j = 0; j < 8; ++j)
        bI[j] = (short)((lg * 8 + j == lr) ? 0x3F80 : 0);

    float c[DCH][MT][4] = {};   // ONLY static indexing below (rule #20)

    __syncthreads();   // nidS ready

    // prologue: stage (t=0, dc=0)
    #pragma unroll
    for (int p = 0; p < 4; ++p) {
        int r = p * 8 + wid * 2 + (lane >> 5);
        int nbr = nidS[r * DEG + 0];
        int lcol = (lane & 31) ^ (r & 7);
        gload_lds16(Hin + (size_t)nbr * FD + (lcol >> 3) * D + (lcol & 7) * 8,
                    &hinS[(p * 8 + wid * 2) * 256]);
    }
    __syncthreads();   // vmcnt(0) drain: hinS ready

    int cur = 0;
    #pragma unroll 1
    for (int t = 0; t < DEG; ++t) {
        #pragma unroll
        for (int dc = 0; dc < DCH; ++dc) {
            // ---- A: acc init from hinS via identity MFMA (swizzled read) ----
            f32x4 acc[4][MT];
            #pragma unroll
            for (int g = 0; g < 4; ++g)
                #pragma unroll
                for (int m = 0; m < MT; ++m) {
                    #pragma unroll
                    for (int r = 0; r < 4; ++r) acc[g][m][r] = 0.f;
                    int pc = (g * 8 + wid * 2 + (lg & 1)) ^ (lr & 7);
                    bf16x8 aI = *(const bf16x8*)&hinS[(m * 16 + lr) * 256 + pc * 8];
                    acc[g][m] = __builtin_amdgcn_mfma_f32_16x16x32_bf16(aI, bI, acc[g][m], 0, 0, 0);
                }
            __syncthreads();   // B: all waves done reading hinS

            // ---- D: recurrent GEMM from packed W (coalesced 1KB chunks) ----
            if (t > 0) {
                const unsigned short* wb = Wbp + ((size_t)dc * 4 + wid) * KCH * 512 + lr * 32 + lg * 8;
                #pragma unroll
                for (int kk = 0; kk < KCH; ++kk) {
                    bf16x8 b[4];
                    #pragma unroll
                    for (int g = 0; g < 4; ++g)
                        b[g] = *(const bf16x8*)&wb[g * GST + kk * 512];
                    #pragma unroll
                    for (int m = 0; m < MT; ++m) {
                        bf16x8 a = *(const bf16x8*)&hS[cur][(m * 16 + lr) * LDA + kk * 32 + lg * 8];
                        #pragma unroll
                        for (int g = 0; g < 4; ++g)
                            acc[g][m] = __builtin_amdgcn_mfma_f32_16x16x32_bf16(a, b[g], acc[g][m], 0, 0, 0);
                    }
                }
            }

            // ---- C: prefetch next (t,dc) slice; issued AFTER W loads (vmcnt FIFO) ----
            __builtin_amdgcn_sched_barrier(0);
            if (!(t == DEG - 1 && dc == DCH - 1)) {
                const int t2  = (dc == DCH - 1) ? t + 1 : t;
                const int dc2 = (dc == DCH - 1) ? 0 : dc + 1;
                #pragma unroll
                for (int p = 0; p < 4; ++p) {
                    int r = p * 8 + wid * 2 + (lane >> 5);
                    int nbr = nidS[r * DEG + t2];
                    int lcol = (lane & 31) ^ (r & 7);
                    gload_lds16(Hin + (size_t)nbr * FD + (lcol >> 3) * D + dc2 * 64 + (lcol & 7) * 8,
                                &hinS[(p * 8 + wid * 2) * 256]);
                }
            }

            // ---- E: LSTM nonlinearity; h_new -> hS[cur^1] (or hout) ----
            #pragma unroll
            for (int m = 0; m < MT; ++m)
                #pragma unroll
                for (int r = 0; r < 4; ++r) {
                    float ig = sigf(acc[0][m][r]);
                    float fg = sigf(acc[1][m][r]);
                    float gg = tanhf_(acc[2][m][r]);
                    float og = sigf(acc[3][m][r]);
                    float cv = fmaf(fg, c[dc][m][r], ig * gg);
                    c[dc][m][r] = cv;
                    float hv = og * tanhf_(cv);
                    if (t < DEG - 1) {
                        hS[cur ^ 1][(m * 16 + lg * 4 + r) * LDA + dc * 64 + wid * 16 + lr] = f2b(hv);
                    } else {
                        int node = nb + m * 16 + lg * 4 + r;
                        if (node < Nn)
                            hout[(size_t)node * D + dc * 64 + wid * 16 + lr] = hv;
                    }
                }

            __syncthreads();   // F: drains gloads (hinS refilled) + hS writes visible
        }
        cur ^= 1;
    }
}

// ---------------- readout ----------------
__global__ void segmax_k(const float* __restrict__ h2, const int* __restrict__ gid,
                         float* __restrict__ hg, int Nn) {
    int g = blockIdx.x;
    int d = threadIdx.x;   // 128
    __shared__ int sb[2];
    if (d < 2) {
        int target = g + d;
        int lo = 0, hi = Nn;
        while (lo < hi) { int mid = (lo + hi) >> 1; if (gid[mid] < target) lo = mid + 1; else hi = mid; }
        sb[d] = lo;
    }
    __syncthreads();
    int lo = sb[0], hi = sb[1];
    float m = -INFINITY;
    for (int r = lo; r < hi; ++r) m = fmaxf(m, h2[(size_t)r * HIDDIM + d]);
    hg[g * HIDDIM + d] = m;
}

__global__ void cls_k(const float* __restrict__ hg, const float* __restrict__ W,
                      const float* __restrict__ b, float* __restrict__ out) {
    int idx = blockIdx.x * 256 + threadIdx.x;
    if (idx >= NGRAPH * NCLS) return;
    int g = idx / NCLS, cc = idx % NCLS;
    float s = b[cc];
    const float* hp = hg + g * HIDDIM;
    const float* wp = W + cc * HIDDIM;
    #pragma unroll 8
    for (int k = 0; k < HIDDIM; ++k) s = fmaf(hp[k], wp[k], s);
    out[idx] = s;
}

extern "C" void kernel_launch(void* const* d_in, const int* in_sizes, int n_in,
                              void* d_out, int out_size, void* d_ws, size_t ws_size,
                              hipStream_t stream)
{
    const float* h       = (const float*)d_in[0];
    const int*   nidx    = (const int*)d_in[1];
    const int*   gids    = (const int*)d_in[2];
    const float* W_ih1   = (const float*)d_in[3];
    const float* W_hh1   = (const float*)d_in[4];
    const float* b_ih1   = (const float*)d_in[5];
    const float* b_hh1   = (const float*)d_in[6];
    const float* W_self1 = (const float*)d_in[7];
    const float* W_neigh1= (const float*)d_in[8];
    const float* b1      = (const float*)d_in[9];
    const float* W_ih2   = (const float*)d_in[10];
    const float* W_hh2   = (const float*)d_in[11];
    const float* b_ih2   = (const float*)d_in[12];
    const float* b_hh2   = (const float*)d_in[13];
    const float* W_self2 = (const float*)d_in[14];
    const float* W_neigh2= (const float*)d_in[15];
    const float* b2      = (const float*)d_in[16];
    const float* W_cls   = (const float*)d_in[17];
    const float* b_cls   = (const float*)d_in[18];
    float* out = (float*)d_out;

    // ws layout (16B-aligned chunks)
    char* ws = (char*)d_ws;
    unsigned short* Hin    = (unsigned short*)(ws);            // 102,400,000
    float*          hneigh = (float*)(ws + 102400000);         //  51,200,000
    float*          h1     = (float*)(ws + 153600000);         //  25,600,000
    float*          h2     = (float*)(ws + 179200000);         //  25,600,000
    float*          hg     = (float*)(ws + 204800000);         //     131,072
    unsigned short* Wb1    = (unsigned short*)(ws + 204931072);//     524,288 (packed)
    unsigned short* Wb2    = (unsigned short*)(ws + 205455360);//     131,072 (packed)

    // W_hh -> packed bf16 B-frag chunks
    packw_k<<<dim3((262144 + 255) / 256), 256, 0, stream>>>(W_hh1, Wb1, 256, 3, 2);
    packw_k<<<dim3((65536 + 255) / 256), 256, 0, stream>>>(W_hh2, Wb2, 128, 2, 1);

    const int MB = (NNODES + 63) / 64;
    const int NB32 = (NNODES + 31) / 32;   // 1563 LSTM blocks

    // ---- conv1 ----
    gemm_nt<false, false, true><<<dim3(1024 / 64, MB), 256, 0, stream>>>(
        h, W_ih1, nullptr, nullptr, b_ih1, b_hh1, Hin, NNODES, 1024, 256, 0);
    lstm_mfma<256, 3><<<dim3(NB32), 256, 0, stream>>>(Hin, Wb1, nidx, hneigh, NNODES);
    gemm_nt<true, true, false><<<dim3(HIDDIM / 64, MB), 256, 0, stream>>>(
        h, W_self1, hneigh, W_neigh1, b1, nullptr, h1, NNODES, HIDDIM, 256, 256);

    // ---- conv2 ----
    gemm_nt<false, false, true><<<dim3(512 / 64, MB), 256, 0, stream>>>(
        h1, W_ih2, nullptr, nullptr, b_ih2, b_hh2, Hin, NNODES, 512, 128, 0);
    lstm_mfma<128, 4><<<dim3(NB32), 256, 0, stream>>>(Hin, Wb2, nidx, hneigh, NNODES);
    gemm_nt<true, true, false><<<dim3(HIDDIM / 64, MB), 256, 0, stream>>>(
        h1, W_self2, hneigh, W_neigh2, b2, nullptr, h2, NNODES, HIDDIM, 128, 128);

    // ---- readout ----
    segmax_k<<<dim3(NGRAPH), 128, 0, stream>>>(h2, gids, hg, NNODES);
    cls_k<<<dim3((NGRAPH * NCLS + 255) / 256), 256, 0, stream>>>(hg, W_cls, b_cls, out);
}

// Round 6
// 3161.654 us; speedup vs baseline: 1.1142x; 1.1142x over previous
//
#include <hip/hip_runtime.h>
#include <hip/hip_bf16.h>

// SAGEClassifier: h[50000,256] --conv1(LSTM-agg)--> h1[50000,128] --conv2--> h2[50000,128]
//   --segment_max(256 graphs)--> hg[256,128] --linear--> out[256,10]
//
// Round 6:
//  (a) REVERT gather staging to cache-allocating reg-staged loads (r5's global_load_lds
//      bypassed L2/L3 on reuse-heavy random gathers: FETCH 3.5GB = pure HBM).
//  (b) 2-iteration-deep gather pipeline: issue G_{ii+2} after iter ii's W-loads (FIFO:
//      W never waits on fresh gathers), publish G_{ii+1} after nonlin, consume at ii+1.
//      Two stg reg sets ping-pong on compile-time dc&1 (rule #20 safe). Single hinS.
//  (c) All dense GEMMs -> MFMA bf16 (gemm_mfma), B pre-packed into per-wave contiguous
//      1KB fragment chunks, A staged bf16 in LDS; activations bf16 end-to-end.

#define NNODES  50000
#define DEG     16
#define INDIM   256
#define HIDDIM  128
#define NCLS    10
#define NGRAPH  256

typedef __hip_bfloat16 bf16;
typedef short bf16x8 __attribute__((ext_vector_type(8)));
typedef float f32x4  __attribute__((ext_vector_type(4)));

__device__ __forceinline__ float sigf(float x) {
    float e = __builtin_amdgcn_exp2f(-1.44269504f * x);
    return __builtin_amdgcn_rcpf(1.0f + e);
}
__device__ __forceinline__ float tanhf_(float x) {
    x = fminf(fmaxf(x, -10.f), 10.f);
    float e = __builtin_amdgcn_exp2f(2.88539008f * x);
    return (e - 1.0f) * __builtin_amdgcn_rcpf(e + 1.0f);
}
__device__ __forceinline__ float b2f(unsigned short u) {
    return __uint_as_float(((unsigned)u) << 16);
}
__device__ __forceinline__ unsigned short f2b(float f) {  // RNE bf16
    unsigned u = __float_as_uint(f);
    return (unsigned short)((u + 0x7FFF + ((u >> 16) & 1)) >> 16);
}

__global__ void f2bf_k(const float* __restrict__ in, unsigned short* __restrict__ out, int n) {
    int i = blockIdx.x * 256 + threadIdx.x;
    if (i < n) out[i] = f2b(in[i]);
}

// Pack W_hh [4D,D] fp32 -> per-(g,dc,wid,kk) contiguous 512-short bf16 chunks
__global__ void packw_k(const float* __restrict__ W, unsigned short* __restrict__ out,
                        int D, int ksh, int dsh) {
    int o = blockIdx.x * 256 + threadIdx.x;
    if (o >= 4 * D * D) return;
    int j  = o & 7;
    int lg = (o >> 3) & 3;
    int lr = (o >> 5) & 15;
    int cch = o >> 9;
    int kk = cch & ((1 << ksh) - 1);
    int c2 = cch >> ksh;
    int wd = c2 & 3;
    int c3 = c2 >> 2;
    int dc = c3 & ((1 << dsh) - 1);
    int g  = c3 >> dsh;
    out[o] = f2b(W[(g * D + dc * 64 + wd * 16 + lr) * D + kk * 32 + lg * 8 + j]);
}

// Pack B [N,K] fp32 -> per-(jt,kk) contiguous 512-short bf16 fragment chunks.
// out[((jt<<ksh)+kk)*512 + lr*32 + lg*8 + j] = B[(jt*16+lr)*K + kk*32+lg*8+j]; ksh=log2(K/32)
__global__ void packb_k(const float* __restrict__ B, unsigned short* __restrict__ out,
                        int N, int K, int ksh) {
    int o = blockIdx.x * 256 + threadIdx.x;
    if (o >= N * K) return;
    int j  = o & 7;
    int lg = (o >> 3) & 3;
    int lr = (o >> 5) & 15;
    int c  = o >> 9;
    int kk = c & ((1 << ksh) - 1);
    int jt = c >> ksh;
    out[o] = f2b(B[(jt * 16 + lr) * K + kk * 32 + lg * 8 + j]);
}

// ---------------- MFMA bf16 GEMM: C = A·B^T (+A2·B2^T) + bias, opt relu ----------------
// 64x64 tile, 4 waves, wave w owns cols [w*16, w*16+16). A bf16 [M,K] staged in LDS;
// B packed (packb_k). C-frag: row = m0+m*16+(lane>>4)*4+reg, col = j0+w*16+(lane&15).
template<bool RELU, bool DUAL, bool BF16OUT>
__global__ __launch_bounds__(256) void gemm_mfma(
    const unsigned short* __restrict__ A,  const unsigned short* __restrict__ Bp,
    const unsigned short* __restrict__ A2, const unsigned short* __restrict__ B2p,
    const float* __restrict__ bias0, const float* __restrict__ bias1,
    void* __restrict__ Cout, int M, int Ncol, int K, int K2, int ksh, int ksh2)
{
    __shared__ unsigned short As[64 * 72];   // [64][64+8] bf16
    const int tid  = threadIdx.x;
    const int wid  = tid >> 6;
    const int lane = tid & 63;
    const int lg   = lane >> 4;
    const int lr   = lane & 15;
    const int m0 = blockIdx.y * 64;
    const int j0 = blockIdx.x * 64;
    const int jt = (j0 >> 4) + wid;

    f32x4 acc[4];
    #pragma unroll
    for (int m = 0; m < 4; ++m)
        #pragma unroll
        for (int r = 0; r < 4; ++r) acc[m][r] = 0.f;

    const int npass = DUAL ? 2 : 1;
    for (int pass = 0; pass < npass; ++pass) {
        const unsigned short* Ap  = (DUAL && pass) ? A2  : A;
        const unsigned short* Bpp = (DUAL && pass) ? B2p : Bp;
        const int Kp   = (DUAL && pass) ? K2   : K;
        const int kshp = (DUAL && pass) ? ksh2 : ksh;
        for (int k0 = 0; k0 < Kp; k0 += 64) {
            __syncthreads();   // prev tile consumed
            #pragma unroll
            for (int p = 0; p < 2; ++p) {
                int i = tid + p * 256;
                int row = i >> 3, c16 = i & 7;
                uint4 v = make_uint4(0u, 0u, 0u, 0u);
                if (m0 + row < M) v = *(const uint4*)&Ap[(size_t)(m0 + row) * Kp + k0 + c16 * 8];
                *(uint4*)&As[row * 72 + c16 * 8] = v;
            }
            __syncthreads();
            #pragma unroll
            for (int kk = 0; kk < 2; ++kk) {
                bf16x8 b = *(const bf16x8*)&Bpp[(size_t)((jt << kshp) + (k0 >> 5) + kk) * 512 + lr * 32 + lg * 8];
                #pragma unroll
                for (int m = 0; m < 4; ++m) {
                    bf16x8 a = *(const bf16x8*)&As[(m * 16 + lr) * 72 + kk * 32 + lg * 8];
                    acc[m] = __builtin_amdgcn_mfma_f32_16x16x32_bf16(a, b, acc[m], 0, 0, 0);
                }
            }
        }
    }
    #pragma unroll
    for (int m = 0; m < 4; ++m)
        #pragma unroll
        for (int r = 0; r < 4; ++r) {
            int row = m0 + m * 16 + lg * 4 + r;
            if (row >= M) continue;
            int col = j0 + wid * 16 + lr;
            float v = acc[m][r];
            if (bias0) v += bias0[col];
            if (bias1) v += bias1[col];
            if (RELU) v = fmaxf(v, 0.f);
            if (BF16OUT) ((unsigned short*)Cout)[(size_t)row * Ncol + col] = f2b(v);
            else         ((float*)Cout)[(size_t)row * Ncol + col] = v;
        }
}

// ---------------- pipelined MFMA fused LSTM ----------------
// 32 nodes/block, 4 waves. Wave w owns d-cols [w*16,w*16+16) of each 64-chunk, all 4
// gates -> i/f/g/o of a (node,d) share a lane+reg. 2-deep gather pipeline (see header).
template<int D>
__global__ __launch_bounds__(256, 2) void lstm_mfma(
    const unsigned short* __restrict__ Hin,   // [Nn,4D] bf16 (bias folded)
    const unsigned short* __restrict__ Wbp,   // packed W_hh (packw_k)
    const int* __restrict__ nidx,             // [Nn,DEG]
    unsigned short* __restrict__ hout,        // [Nn,D] bf16
    int Nn)
{
    constexpr int FD  = 4 * D;
    constexpr int KCH = D / 32;
    constexpr int DCH = D / 64;
    constexpr int TN  = 32;
    constexpr int MT  = 2;
    constexpr int LDA = D + 8;
    constexpr int LDH = 264;
    constexpr int GST = DCH * 4 * KCH * 512;
    constexpr int NIT = DEG * DCH;

    __shared__ unsigned short hS[2][TN * LDA];   // dbuf h_state
    __shared__ unsigned short hinS[TN * LDH];    // gathered Hin slice (single buf)
    __shared__ int nidS[TN * DEG];

    const int tid  = threadIdx.x;
    const int wid  = tid >> 6;
    const int lane = tid & 63;
    const int lg   = lane >> 4;
    const int lr   = lane & 15;
    const int nb   = blockIdx.x * TN;
    const int srow = tid >> 5;    // staging base row (0..7)
    const int slot = tid & 31;    // 16B slot within 512B slice
    const int sg   = slot >> 3;   // gate
    const int sc8  = slot & 7;

    for (int i = tid; i < TN * DEG; i += 256) {
        int node = nb + (i >> 4);
        nidS[i] = (node < Nn) ? nidx[node * DEG + (i & 15)] : 0;
    }

    // identity B-fragment: B[col=lr][k=lg*8+j] = (lg*8+j == lr)
    bf16x8 bI;
    #pragma unroll
    for (int j = 0; j < 8; ++j)
        bI[j] = (short)((lg * 8 + j == lr) ? 0x3F80 : 0);

    float c[DCH][MT][4] = {};   // static indexing only (rule #20)
    uint4 sA[4], sB[4];         // 2-deep prefetch reg sets (ping-pong on dc&1)

    auto ISSUE = [&](uint4 (&s)[4], int t2, int dc2) {
        #pragma unroll
        for (int it = 0; it < 4; ++it) {
            int nbr = nidS[(srow + it * 8) * DEG + t2];
            s[it] = *(const uint4*)&Hin[(size_t)nbr * FD + sg * D + dc2 * 64 + sc8 * 8];
        }
    };
    auto PUB = [&](uint4 (&s)[4]) {
        #pragma unroll
        for (int it = 0; it < 4; ++it)
            *(uint4*)&hinS[(srow + it * 8) * LDH + slot * 8] = s[it];
    };

    __syncthreads();            // nidS ready
    ISSUE(sA, 0, 0);            // G0
    ISSUE(sB, 0, 1 % DCH);      // G1 (DCH>=2 always)
    PUB(sA);                    // waits only G0 (G1 younger in FIFO)
    __syncthreads();

    int cur = 0;
    #pragma unroll 1
    for (int t = 0; t < DEG; ++t) {
        #pragma unroll
        for (int dc = 0; dc < DCH; ++dc) {
            const int ii = t * DCH + dc;

            // ---- A: acc init from hinS via identity MFMA ----
            f32x4 acc[4][MT];
            #pragma unroll
            for (int g = 0; g < 4; ++g)
                #pragma unroll
                for (int m = 0; m < MT; ++m) {
                    #pragma unroll
                    for (int r = 0; r < 4; ++r) acc[g][m][r] = 0.f;
                    bf16x8 aI = *(const bf16x8*)&hinS[(m * 16 + lr) * LDH + g * 64 + wid * 16 + (lg & 1) * 8];
                    acc[g][m] = __builtin_amdgcn_mfma_f32_16x16x32_bf16(aI, bI, acc[g][m], 0, 0, 0);
                }
            __syncthreads();   // all waves done reading hinS

            // ---- D: recurrent GEMM (packed W, coalesced 1KB chunks, L2-resident) ----
            if (t > 0) {
                const unsigned short* wb = Wbp + ((size_t)dc * 4 + wid) * KCH * 512 + lr * 32 + lg * 8;
                #pragma unroll
                for (int kk = 0; kk < KCH; ++kk) {
                    bf16x8 b[4];
                    #pragma unroll
                    for (int g = 0; g < 4; ++g)
                        b[g] = *(const bf16x8*)&wb[g * GST + kk * 512];
                    #pragma unroll
                    for (int m = 0; m < MT; ++m) {
                        bf16x8 a = *(const bf16x8*)&hS[cur][(m * 16 + lr) * LDA + kk * 32 + lg * 8];
                        #pragma unroll
                        for (int g = 0; g < 4; ++g)
                            acc[g][m] = __builtin_amdgcn_mfma_f32_16x16x32_bf16(a, b[g], acc[g][m], 0, 0, 0);
                    }
                }
            }

            // ---- issue G_{ii+2} (after W-loads: FIFO keeps W waits gather-free) ----
            if (ii + 2 < NIT) {
                const int t2  = (dc + 2 >= DCH) ? t + 1 : t;
                const int dc2 = (dc + 2) % DCH;          // compile-time
                if (dc & 1) ISSUE(sB, t2, dc2); else ISSUE(sA, t2, dc2);
            }

            // ---- E: LSTM nonlinearity; h_new -> hS[cur^1] (or hout bf16) ----
            #pragma unroll
            for (int m = 0; m < MT; ++m)
                #pragma unroll
                for (int r = 0; r < 4; ++r) {
                    float ig = sigf(acc[0][m][r]);
                    float fg = sigf(acc[1][m][r]);
                    float gg = tanhf_(acc[2][m][r]);
                    float og = sigf(acc[3][m][r]);
                    float cv = fmaf(fg, c[dc][m][r], ig * gg);
                    c[dc][m][r] = cv;
                    float hv = og * tanhf_(cv);
                    if (t < DEG - 1) {
                        hS[cur ^ 1][(m * 16 + lg * 4 + r) * LDA + dc * 64 + wid * 16 + lr] = f2b(hv);
                    } else {
                        int node = nb + m * 16 + lg * 4 + r;
                        if (node < Nn)
                            hout[(size_t)node * D + dc * 64 + wid * 16 + lr] = f2b(hv);
                    }
                }

            // ---- publish G_{ii+1} (issued last iter: ~1 full iter in flight) ----
            if (ii + 1 < NIT) {
                if ((dc + 1) & 1) PUB(sB); else PUB(sA);
            }
            __syncthreads();
        }
        cur ^= 1;
    }
}

// ---------------- readout ----------------
__global__ void segmax_k(const unsigned short* __restrict__ h2, const int* __restrict__ gid,
                         float* __restrict__ hg, int Nn) {
    int g = blockIdx.x;
    int d = threadIdx.x;   // 128
    __shared__ int sb[2];
    if (d < 2) {
        int target = g + d;
        int lo = 0, hi = Nn;
        while (lo < hi) { int mid = (lo + hi) >> 1; if (gid[mid] < target) lo = mid + 1; else hi = mid; }
        sb[d] = lo;
    }
    __syncthreads();
    int lo = sb[0], hi = sb[1];
    float m = -INFINITY;
    for (int r = lo; r < hi; ++r) m = fmaxf(m, b2f(h2[(size_t)r * HIDDIM + d]));
    hg[g * HIDDIM + d] = m;
}

__global__ void cls_k(const float* __restrict__ hg, const float* __restrict__ W,
                      const float* __restrict__ b, float* __restrict__ out) {
    int idx = blockIdx.x * 256 + threadIdx.x;
    if (idx >= NGRAPH * NCLS) return;
    int g = idx / NCLS, cc = idx % NCLS;
    float s = b[cc];
    const float* hp = hg + g * HIDDIM;
    const float* wp = W + cc * HIDDIM;
    #pragma unroll 8
    for (int k = 0; k < HIDDIM; ++k) s = fmaf(hp[k], wp[k], s);
    out[idx] = s;
}

extern "C" void kernel_launch(void* const* d_in, const int* in_sizes, int n_in,
                              void* d_out, int out_size, void* d_ws, size_t ws_size,
                              hipStream_t stream)
{
    const float* h       = (const float*)d_in[0];
    const int*   nidx    = (const int*)d_in[1];
    const int*   gids    = (const int*)d_in[2];
    const float* W_ih1   = (const float*)d_in[3];
    const float* W_hh1   = (const float*)d_in[4];
    const float* b_ih1   = (const float*)d_in[5];
    const float* b_hh1   = (const float*)d_in[6];
    const float* W_self1 = (const float*)d_in[7];
    const float* W_neigh1= (const float*)d_in[8];
    const float* b1      = (const float*)d_in[9];
    const float* W_ih2   = (const float*)d_in[10];
    const float* W_hh2   = (const float*)d_in[11];
    const float* b_ih2   = (const float*)d_in[12];
    const float* b_hh2   = (const float*)d_in[13];
    const float* W_self2 = (const float*)d_in[14];
    const float* W_neigh2= (const float*)d_in[15];
    const float* b2      = (const float*)d_in[16];
    const float* W_cls   = (const float*)d_in[17];
    const float* b_cls   = (const float*)d_in[18];
    float* out = (float*)d_out;

    // ws layout (bf16 activations)
    char* ws = (char*)d_ws;
    unsigned short* Hin   = (unsigned short*)(ws);             // 102,400,000
    unsigned short* hb    = (unsigned short*)(ws + 102400000); //  25,600,000
    unsigned short* hnb   = (unsigned short*)(ws + 128000000); //  25,600,000 (lstm out)
    unsigned short* h1b   = (unsigned short*)(ws + 153600000); //  12,800,000
    unsigned short* h2b   = (unsigned short*)(ws + 166400000); //  12,800,000
    float*          hg    = (float*)(ws + 179200000);          //     131,072
    unsigned short* Whh1p = (unsigned short*)(ws + 179331072); //     524,288
    unsigned short* Whh2p = (unsigned short*)(ws + 179855360); //     131,072
    unsigned short* Wih1p = (unsigned short*)(ws + 179986432); //     524,288
    unsigned short* Wih2p = (unsigned short*)(ws + 180510720); //     131,072
    unsigned short* Wsl1p = (unsigned short*)(ws + 180641792); //      65,536
    unsigned short* Wng1p = (unsigned short*)(ws + 180707328); //      65,536
    unsigned short* Wsl2p = (unsigned short*)(ws + 180772864); //      32,768
    unsigned short* Wng2p = (unsigned short*)(ws + 180805632); //      32,768

    // prep: conversions + packing (all tiny)
    f2bf_k<<<dim3(50000), 256, 0, stream>>>(h, hb, NNODES * INDIM);
    packw_k<<<dim3(1024), 256, 0, stream>>>(W_hh1, Whh1p, 256, 3, 2);
    packw_k<<<dim3(256), 256, 0, stream>>>(W_hh2, Whh2p, 128, 2, 1);
    packb_k<<<dim3(1024), 256, 0, stream>>>(W_ih1, Wih1p, 1024, 256, 3);
    packb_k<<<dim3(256), 256, 0, stream>>>(W_ih2, Wih2p, 512, 128, 2);
    packb_k<<<dim3(128), 256, 0, stream>>>(W_self1, Wsl1p, 128, 256, 3);
    packb_k<<<dim3(128), 256, 0, stream>>>(W_neigh1, Wng1p, 128, 256, 3);
    packb_k<<<dim3(64), 256, 0, stream>>>(W_self2, Wsl2p, 128, 128, 2);
    packb_k<<<dim3(64), 256, 0, stream>>>(W_neigh2, Wng2p, 128, 128, 2);

    const int MB = (NNODES + 63) / 64;     // 782
    const int NB32 = (NNODES + 31) / 32;   // 1563

    // ---- conv1 ----
    gemm_mfma<false, false, true><<<dim3(1024 / 64, MB), 256, 0, stream>>>(
        hb, Wih1p, nullptr, nullptr, b_ih1, b_hh1, Hin, NNODES, 1024, 256, 0, 3, 0);
    lstm_mfma<256><<<dim3(NB32), 256, 0, stream>>>(Hin, Whh1p, nidx, hnb, NNODES);
    gemm_mfma<true, true, true><<<dim3(HIDDIM / 64, MB), 256, 0, stream>>>(
        hb, Wsl1p, hnb, Wng1p, b1, nullptr, h1b, NNODES, HIDDIM, 256, 256, 3, 3);

    // ---- conv2 ----
    gemm_mfma<false, false, true><<<dim3(512 / 64, MB), 256, 0, stream>>>(
        h1b, Wih2p, nullptr, nullptr, b_ih2, b_hh2, Hin, NNODES, 512, 128, 0, 2, 0);
    lstm_mfma<128><<<dim3(NB32), 256, 0, stream>>>(Hin, Whh2p, nidx, hnb, NNODES);
    gemm_mfma<true, true, true><<<dim3(HIDDIM / 64, MB), 256, 0, stream>>>(
        h1b, Wsl2p, hnb, Wng2p, b2, nullptr, h2b, NNODES, HIDDIM, 128, 128, 2, 2);

    // ---- readout ----
    segmax_k<<<dim3(NGRAPH), 128, 0, stream>>>(h2b, gids, hg, NNODES);
    cls_k<<<dim3((NGRAPH * NCLS + 255) / 256), 256, 0, stream>>>(hg, W_cls, b_cls, out);
}

// Round 7
// 2871.128 us; speedup vs baseline: 1.2270x; 1.1012x over previous
//
#include <hip/hip_runtime.h>
#include <hip/hip_bf16.h>

// SAGEClassifier: h[50000,256] --conv1(LSTM-agg)--> h1[50000,128] --conv2--> h2[50000,128]
//   --segment_max(256 graphs)--> hg[256,128] --linear--> out[256,10]
//
// Round 7: r6's ping-pong staging arrays (uint4 sA[4]/sB[4] passed by REFERENCE into
// lambdas) were address-taken -> scratch (WRITE_SIZE 1.8GB, the whole regression).
// Fix: 8 individually named uint4 registers + macros; all accesses static.
// Everything else frozen from r6 (cache-allocating reg-staged gathers, 2-deep
// pipeline, MFMA bf16 GEMMs, packed B operands, bf16 activations).

#define NNODES  50000
#define DEG     16
#define INDIM   256
#define HIDDIM  128
#define NCLS    10
#define NGRAPH  256

typedef __hip_bfloat16 bf16;
typedef short bf16x8 __attribute__((ext_vector_type(8)));
typedef float f32x4  __attribute__((ext_vector_type(4)));

__device__ __forceinline__ float sigf(float x) {
    float e = __builtin_amdgcn_exp2f(-1.44269504f * x);
    return __builtin_amdgcn_rcpf(1.0f + e);
}
__device__ __forceinline__ float tanhf_(float x) {
    x = fminf(fmaxf(x, -10.f), 10.f);
    float e = __builtin_amdgcn_exp2f(2.88539008f * x);
    return (e - 1.0f) * __builtin_amdgcn_rcpf(e + 1.0f);
}
__device__ __forceinline__ float b2f(unsigned short u) {
    return __uint_as_float(((unsigned)u) << 16);
}
__device__ __forceinline__ unsigned short f2b(float f) {  // RNE bf16
    unsigned u = __float_as_uint(f);
    return (unsigned short)((u + 0x7FFF + ((u >> 16) & 1)) >> 16);
}

__global__ void f2bf_k(const float* __restrict__ in, unsigned short* __restrict__ out, int n) {
    int i = blockIdx.x * 256 + threadIdx.x;
    if (i < n) out[i] = f2b(in[i]);
}

// Pack W_hh [4D,D] fp32 -> per-(g,dc,wid,kk) contiguous 512-short bf16 chunks
__global__ void packw_k(const float* __restrict__ W, unsigned short* __restrict__ out,
                        int D, int ksh, int dsh) {
    int o = blockIdx.x * 256 + threadIdx.x;
    if (o >= 4 * D * D) return;
    int j  = o & 7;
    int lg = (o >> 3) & 3;
    int lr = (o >> 5) & 15;
    int cch = o >> 9;
    int kk = cch & ((1 << ksh) - 1);
    int c2 = cch >> ksh;
    int wd = c2 & 3;
    int c3 = c2 >> 2;
    int dc = c3 & ((1 << dsh) - 1);
    int g  = c3 >> dsh;
    out[o] = f2b(W[(g * D + dc * 64 + wd * 16 + lr) * D + kk * 32 + lg * 8 + j]);
}

// Pack B [N,K] fp32 -> per-(jt,kk) contiguous 512-short bf16 fragment chunks.
__global__ void packb_k(const float* __restrict__ B, unsigned short* __restrict__ out,
                        int N, int K, int ksh) {
    int o = blockIdx.x * 256 + threadIdx.x;
    if (o >= N * K) return;
    int j  = o & 7;
    int lg = (o >> 3) & 3;
    int lr = (o >> 5) & 15;
    int c  = o >> 9;
    int kk = c & ((1 << ksh) - 1);
    int jt = c >> ksh;
    out[o] = f2b(B[(jt * 16 + lr) * K + kk * 32 + lg * 8 + j]);
}

// ---------------- MFMA bf16 GEMM: C = A·B^T (+A2·B2^T) + bias, opt relu ----------------
template<bool RELU, bool DUAL, bool BF16OUT>
__global__ __launch_bounds__(256) void gemm_mfma(
    const unsigned short* __restrict__ A,  const unsigned short* __restrict__ Bp,
    const unsigned short* __restrict__ A2, const unsigned short* __restrict__ B2p,
    const float* __restrict__ bias0, const float* __restrict__ bias1,
    void* __restrict__ Cout, int M, int Ncol, int K, int K2, int ksh, int ksh2)
{
    __shared__ unsigned short As[64 * 72];   // [64][64+8] bf16
    const int tid  = threadIdx.x;
    const int wid  = tid >> 6;
    const int lane = tid & 63;
    const int lg   = lane >> 4;
    const int lr   = lane & 15;
    const int m0 = blockIdx.y * 64;
    const int j0 = blockIdx.x * 64;
    const int jt = (j0 >> 4) + wid;

    f32x4 acc[4];
    #pragma unroll
    for (int m = 0; m < 4; ++m)
        #pragma unroll
        for (int r = 0; r < 4; ++r) acc[m][r] = 0.f;

    const int npass = DUAL ? 2 : 1;
    for (int pass = 0; pass < npass; ++pass) {
        const unsigned short* Ap  = (DUAL && pass) ? A2  : A;
        const unsigned short* Bpp = (DUAL && pass) ? B2p : Bp;
        const int Kp   = (DUAL && pass) ? K2   : K;
        const int kshp = (DUAL && pass) ? ksh2 : ksh;
        for (int k0 = 0; k0 < Kp; k0 += 64) {
            __syncthreads();   // prev tile consumed
            #pragma unroll
            for (int p = 0; p < 2; ++p) {
                int i = tid + p * 256;
                int row = i >> 3, c16 = i & 7;
                uint4 v = make_uint4(0u, 0u, 0u, 0u);
                if (m0 + row < M) v = *(const uint4*)&Ap[(size_t)(m0 + row) * Kp + k0 + c16 * 8];
                *(uint4*)&As[row * 72 + c16 * 8] = v;
            }
            __syncthreads();
            #pragma unroll
            for (int kk = 0; kk < 2; ++kk) {
                bf16x8 b = *(const bf16x8*)&Bpp[(size_t)((jt << kshp) + (k0 >> 5) + kk) * 512 + lr * 32 + lg * 8];
                #pragma unroll
                for (int m = 0; m < 4; ++m) {
                    bf16x8 a = *(const bf16x8*)&As[(m * 16 + lr) * 72 + kk * 32 + lg * 8];
                    acc[m] = __builtin_amdgcn_mfma_f32_16x16x32_bf16(a, b, acc[m], 0, 0, 0);
                }
            }
        }
    }
    #pragma unroll
    for (int m = 0; m < 4; ++m)
        #pragma unroll
        for (int r = 0; r < 4; ++r) {
            int row = m0 + m * 16 + lg * 4 + r;
            if (row >= M) continue;
            int col = j0 + wid * 16 + lr;
            float v = acc[m][r];
            if (bias0) v += bias0[col];
            if (bias1) v += bias1[col];
            if (RELU) v = fmaxf(v, 0.f);
            if (BF16OUT) ((unsigned short*)Cout)[(size_t)row * Ncol + col] = f2b(v);
            else         ((float*)Cout)[(size_t)row * Ncol + col] = v;
        }
}

// ---------------- pipelined MFMA fused LSTM ----------------
// 32 nodes/block, 4 waves. Wave w owns d-cols [w*16,w*16+16) of each 64-chunk, all 4
// gates -> i/f/g/o of a (node,d) share a lane+reg. 2-deep gather pipeline; staging
// held in 8 NAMED uint4 regs (sA0..sB3) -- no arrays, no lambdas (scratch-proof).

#define ISSUE_M(s0, s1, s2, s3, tt, dd)                                                        \
    {                                                                                          \
        s0 = *(const uint4*)&Hin[(size_t)nidS[(srow     ) * DEG + (tt)] * FD + sg * D + (dd) * 64 + sc8 * 8]; \
        s1 = *(const uint4*)&Hin[(size_t)nidS[(srow +  8) * DEG + (tt)] * FD + sg * D + (dd) * 64 + sc8 * 8]; \
        s2 = *(const uint4*)&Hin[(size_t)nidS[(srow + 16) * DEG + (tt)] * FD + sg * D + (dd) * 64 + sc8 * 8]; \
        s3 = *(const uint4*)&Hin[(size_t)nidS[(srow + 24) * DEG + (tt)] * FD + sg * D + (dd) * 64 + sc8 * 8]; \
    }
#define PUB_M(s0, s1, s2, s3)                                      \
    {                                                              \
        *(uint4*)&hinS[(srow     ) * LDH + slot * 8] = s0;         \
        *(uint4*)&hinS[(srow +  8) * LDH + slot * 8] = s1;         \
        *(uint4*)&hinS[(srow + 16) * LDH + slot * 8] = s2;         \
        *(uint4*)&hinS[(srow + 24) * LDH + slot * 8] = s3;         \
    }

template<int D, int MINW>
__global__ __launch_bounds__(256, MINW) void lstm_mfma(
    const unsigned short* __restrict__ Hin,   // [Nn,4D] bf16 (bias folded)
    const unsigned short* __restrict__ Wbp,   // packed W_hh (packw_k)
    const int* __restrict__ nidx,             // [Nn,DEG]
    unsigned short* __restrict__ hout,        // [Nn,D] bf16
    int Nn)
{
    constexpr int FD  = 4 * D;
    constexpr int KCH = D / 32;
    constexpr int DCH = D / 64;
    constexpr int TN  = 32;
    constexpr int MT  = 2;
    constexpr int LDA = D + 8;
    constexpr int LDH = 264;
    constexpr int GST = DCH * 4 * KCH * 512;
    constexpr int NIT = DEG * DCH;

    __shared__ unsigned short hS[2][TN * LDA];   // dbuf h_state
    __shared__ unsigned short hinS[TN * LDH];    // gathered Hin slice (single buf)
    __shared__ int nidS[TN * DEG];

    const int tid  = threadIdx.x;
    const int wid  = tid >> 6;
    const int lane = tid & 63;
    const int lg   = lane >> 4;
    const int lr   = lane & 15;
    const int nb   = blockIdx.x * TN;
    const int srow = tid >> 5;    // staging base row (0..7)
    const int slot = tid & 31;    // 16B slot within 512B slice
    const int sg   = slot >> 3;   // gate
    const int sc8  = slot & 7;

    for (int i = tid; i < TN * DEG; i += 256) {
        int node = nb + (i >> 4);
        nidS[i] = (node < Nn) ? nidx[node * DEG + (i & 15)] : 0;
    }

    // identity B-fragment: B[col=lr][k=lg*8+j] = (lg*8+j == lr)
    bf16x8 bI;
    #pragma unroll
    for (int j = 0; j < 8; ++j)
        bI[j] = (short)((lg * 8 + j == lr) ? 0x3F80 : 0);

    float c[DCH][MT][4] = {};               // static indexing only (rule #20)
    uint4 sA0, sA1, sA2, sA3;               // named staging regs (never address-taken)
    uint4 sB0, sB1, sB2, sB3;

    __syncthreads();                        // nidS ready
    ISSUE_M(sA0, sA1, sA2, sA3, 0, 0)       // G0
    ISSUE_M(sB0, sB1, sB2, sB3, 0, 1)       // G1 (DCH>=2 always)
    PUB_M(sA0, sA1, sA2, sA3)               // waits only G0 (G1 younger in FIFO)
    __syncthreads();

    int cur = 0;
    #pragma unroll 1
    for (int t = 0; t < DEG; ++t) {
        #pragma unroll
        for (int dc = 0; dc < DCH; ++dc) {
            const int ii = t * DCH + dc;

            // ---- acc init from hinS (holds G_ii) via identity MFMA ----
            f32x4 acc[4][MT];
            #pragma unroll
            for (int g = 0; g < 4; ++g)
                #pragma unroll
                for (int m = 0; m < MT; ++m) {
                    #pragma unroll
                    for (int r = 0; r < 4; ++r) acc[g][m][r] = 0.f;
                    bf16x8 aI = *(const bf16x8*)&hinS[(m * 16 + lr) * LDH + g * 64 + wid * 16 + (lg & 1) * 8];
                    acc[g][m] = __builtin_amdgcn_mfma_f32_16x16x32_bf16(aI, bI, acc[g][m], 0, 0, 0);
                }
            __syncthreads();   // all waves done reading hinS

            // ---- recurrent GEMM (packed W, coalesced 1KB chunks, L2-resident) ----
            if (t > 0) {
                const unsigned short* wb = Wbp + ((size_t)dc * 4 + wid) * KCH * 512 + lr * 32 + lg * 8;
                #pragma unroll
                for (int kk = 0; kk < KCH; ++kk) {
                    bf16x8 b[4];
                    #pragma unroll
                    for (int g = 0; g < 4; ++g)
                        b[g] = *(const bf16x8*)&wb[g * GST + kk * 512];
                    #pragma unroll
                    for (int m = 0; m < MT; ++m) {
                        bf16x8 a = *(const bf16x8*)&hS[cur][(m * 16 + lr) * LDA + kk * 32 + lg * 8];
                        #pragma unroll
                        for (int g = 0; g < 4; ++g)
                            acc[g][m] = __builtin_amdgcn_mfma_f32_16x16x32_bf16(a, b[g], acc[g][m], 0, 0, 0);
                    }
                }
            }

            // ---- issue G_{ii+2} (after W-loads: FIFO keeps W waits gather-free) ----
            if (ii + 2 < NIT) {
                const int t2 = (dc + 2 >= DCH) ? t + 1 : t;
                if (dc & 1) { ISSUE_M(sB0, sB1, sB2, sB3, t2, (dc + 2) % DCH) }
                else        { ISSUE_M(sA0, sA1, sA2, sA3, t2, (dc + 2) % DCH) }
            }

            // ---- LSTM nonlinearity; h_new -> hS[cur^1] (or hout bf16) ----
            #pragma unroll
            for (int m = 0; m < MT; ++m)
                #pragma unroll
                for (int r = 0; r < 4; ++r) {
                    float ig = sigf(acc[0][m][r]);
                    float fg = sigf(acc[1][m][r]);
                    float gg = tanhf_(acc[2][m][r]);
                    float og = sigf(acc[3][m][r]);
                    float cv = fmaf(fg, c[dc][m][r], ig * gg);
                    c[dc][m][r] = cv;
                    float hv = og * tanhf_(cv);
                    if (t < DEG - 1) {
                        hS[cur ^ 1][(m * 16 + lg * 4 + r) * LDA + dc * 64 + wid * 16 + lr] = f2b(hv);
                    } else {
                        int node = nb + m * 16 + lg * 4 + r;
                        if (node < Nn)
                            hout[(size_t)node * D + dc * 64 + wid * 16 + lr] = f2b(hv);
                    }
                }

            // ---- publish G_{ii+1} (issued one iter ago: full iter of latency hidden) ----
            if (ii + 1 < NIT) {
                if ((dc + 1) & 1) { PUB_M(sB0, sB1, sB2, sB3) }
                else              { PUB_M(sA0, sA1, sA2, sA3) }
            }
            __syncthreads();
        }
        cur ^= 1;
    }
}

// ---------------- readout ----------------
__global__ void segmax_k(const unsigned short* __restrict__ h2, const int* __restrict__ gid,
                         float* __restrict__ hg, int Nn) {
    int g = blockIdx.x;
    int d = threadIdx.x;   // 128
    __shared__ int sb[2];
    if (d < 2) {
        int target = g + d;
        int lo = 0, hi = Nn;
        while (lo < hi) { int mid = (lo + hi) >> 1; if (gid[mid] < target) lo = mid + 1; else hi = mid; }
        sb[d] = lo;
    }
    __syncthreads();
    int lo = sb[0], hi = sb[1];
    float m = -INFINITY;
    for (int r = lo; r < hi; ++r) m = fmaxf(m, b2f(h2[(size_t)r * HIDDIM + d]));
    hg[g * HIDDIM + d] = m;
}

__global__ void cls_k(const float* __restrict__ hg, const float* __restrict__ W,
                      const float* __restrict__ b, float* __restrict__ out) {
    int idx = blockIdx.x * 256 + threadIdx.x;
    if (idx >= NGRAPH * NCLS) return;
    int g = idx / NCLS, cc = idx % NCLS;
    float s = b[cc];
    const float* hp = hg + g * HIDDIM;
    const float* wp = W + cc * HIDDIM;
    #pragma unroll 8
    for (int k = 0; k < HIDDIM; ++k) s = fmaf(hp[k], wp[k], s);
    out[idx] = s;
}

extern "C" void kernel_launch(void* const* d_in, const int* in_sizes, int n_in,
                              void* d_out, int out_size, void* d_ws, size_t ws_size,
                              hipStream_t stream)
{
    const float* h       = (const float*)d_in[0];
    const int*   nidx    = (const int*)d_in[1];
    const int*   gids    = (const int*)d_in[2];
    const float* W_ih1   = (const float*)d_in[3];
    const float* W_hh1   = (const float*)d_in[4];
    const float* b_ih1   = (const float*)d_in[5];
    const float* b_hh1   = (const float*)d_in[6];
    const float* W_self1 = (const float*)d_in[7];
    const float* W_neigh1= (const float*)d_in[8];
    const float* b1      = (const float*)d_in[9];
    const float* W_ih2   = (const float*)d_in[10];
    const float* W_hh2   = (const float*)d_in[11];
    const float* b_ih2   = (const float*)d_in[12];
    const float* b_hh2   = (const float*)d_in[13];
    const float* W_self2 = (const float*)d_in[14];
    const float* W_neigh2= (const float*)d_in[15];
    const float* b2      = (const float*)d_in[16];
    const float* W_cls   = (const float*)d_in[17];
    const float* b_cls   = (const float*)d_in[18];
    float* out = (float*)d_out;

    // ws layout (bf16 activations)
    char* ws = (char*)d_ws;
    unsigned short* Hin   = (unsigned short*)(ws);             // 102,400,000
    unsigned short* hb    = (unsigned short*)(ws + 102400000); //  25,600,000
    unsigned short* hnb   = (unsigned short*)(ws + 128000000); //  25,600,000 (lstm out)
    unsigned short* h1b   = (unsigned short*)(ws + 153600000); //  12,800,000
    unsigned short* h2b   = (unsigned short*)(ws + 166400000); //  12,800,000
    float*          hg    = (float*)(ws + 179200000);          //     131,072
    unsigned short* Whh1p = (unsigned short*)(ws + 179331072); //     524,288
    unsigned short* Whh2p = (unsigned short*)(ws + 179855360); //     131,072
    unsigned short* Wih1p = (unsigned short*)(ws + 179986432); //     524,288
    unsigned short* Wih2p = (unsigned short*)(ws + 180510720); //     131,072
    unsigned short* Wsl1p = (unsigned short*)(ws + 180641792); //      65,536
    unsigned short* Wng1p = (unsigned short*)(ws + 180707328); //      65,536
    unsigned short* Wsl2p = (unsigned short*)(ws + 180772864); //      32,768
    unsigned short* Wng2p = (unsigned short*)(ws + 180805632); //      32,768

    // prep: conversions + packing (all tiny)
    f2bf_k<<<dim3(50000), 256, 0, stream>>>(h, hb, NNODES * INDIM);
    packw_k<<<dim3(1024), 256, 0, stream>>>(W_hh1, Whh1p, 256, 3, 2);
    packw_k<<<dim3(256), 256, 0, stream>>>(W_hh2, Whh2p, 128, 2, 1);
    packb_k<<<dim3(1024), 256, 0, stream>>>(W_ih1, Wih1p, 1024, 256, 3);
    packb_k<<<dim3(256), 256, 0, stream>>>(W_ih2, Wih2p, 512, 128, 2);
    packb_k<<<dim3(128), 256, 0, stream>>>(W_self1, Wsl1p, 128, 256, 3);
    packb_k<<<dim3(128), 256, 0, stream>>>(W_neigh1, Wng1p, 128, 256, 3);
    packb_k<<<dim3(64), 256, 0, stream>>>(W_self2, Wsl2p, 128, 128, 2);
    packb_k<<<dim3(64), 256, 0, stream>>>(W_neigh2, Wng2p, 128, 128, 2);

    const int MB = (NNODES + 63) / 64;     // 782
    const int NB32 = (NNODES + 31) / 32;   // 1563

    // ---- conv1 ----
    gemm_mfma<false, false, true><<<dim3(1024 / 64, MB), 256, 0, stream>>>(
        hb, Wih1p, nullptr, nullptr, b_ih1, b_hh1, Hin, NNODES, 1024, 256, 0, 3, 0);
    lstm_mfma<256, 2><<<dim3(NB32), 256, 0, stream>>>(Hin, Whh1p, nidx, hnb, NNODES);
    gemm_mfma<true, true, true><<<dim3(HIDDIM / 64, MB), 256, 0, stream>>>(
        hb, Wsl1p, hnb, Wng1p, b1, nullptr, h1b, NNODES, HIDDIM, 256, 256, 3, 3);

    // ---- conv2 ----
    gemm_mfma<false, false, true><<<dim3(512 / 64, MB), 256, 0, stream>>>(
        h1b, Wih2p, nullptr, nullptr, b_ih2, b_hh2, Hin, NNODES, 512, 128, 0, 2, 0);
    lstm_mfma<128, 3><<<dim3(NB32), 256, 0, stream>>>(Hin, Whh2p, nidx, hnb, NNODES);
    gemm_mfma<true, true, true><<<dim3(HIDDIM / 64, MB), 256, 0, stream>>>(
        h1b, Wsl2p, hnb, Wng2p, b2, nullptr, h2b, NNODES, HIDDIM, 128, 128, 2, 2);

    // ---- readout ----
    segmax_k<<<dim3(NGRAPH), 128, 0, stream>>>(h2b, gids, hg, NNODES);
    cls_k<<<dim3((NGRAPH * NCLS + 255) / 256), 256, 0, stream>>>(hg, W_cls, b_cls, out);
}